// Round 3
// baseline (125.633 us; speedup 1.0000x reference)
//
#include <hip/hip_runtime.h>
#include <math.h>

// TDVP_V2: BATCH=16384 chains, N=64 sites, D=4, DIN=DOUT=2.
// v19: CALIBRATION EXPERIMENT. v15/v17/v18 (radically different structures:
// LDS-operand vs scalar-operand vs 2x occupancy) measured 77.698/77.754/77.696
// — 0.06 us spread. A real ~25-35 us kernel cannot tie to 0.2% across three
// instruction mixes => suspect the ~35.7 us residual (77.7 - 42 us poison
// fill) is mostly fixed graph overhead (7 dispatches/iter: top-5 fill
// dispatch-id deltas 35/70/91/126/168/182/301 all divisible by 7), not kernel.
// This kernel repeats the full compute REP=5x with an opaque per-rep zero
// (asm v_mov) added to the normalized x components so LICM cannot hoist reps;
// values are bit-identical (x+0.0f), output = last rep. Barriers preserve
// single-pass LDS semantics per rep.
// PRE-COMMITTED READING:
//   dur ~ 77.7 + 4K (K = true kernel time). K~25 => ~175 us and tdvp_kernel
//   surfaces in top-5 with real counters. K~5 => ~98 us.
//   dur unchanged => kernel not on timed critical path => harness floor;
//   revert to fastest variant and declare floor next round.

#define EPS 1e-6f
#define RSQ(x) __builtin_amdgcn_rsqf((x) + 1e-30f)
#define REP 5

#define BUILD_M(Mk, Ak, xav, xcv)                                   \
    {                                                               \
        _Pragma("unroll")                                           \
        for (int e = 0; e < 16; ++e)                                \
            Mk[e] = fmaf((xcv), (Ak)[2*e+1], (xav) * (Ak)[2*e]);    \
    }

__global__ __launch_bounds__(1024, 4)
void tdvp_kernel(const float* __restrict__ x,
                 const float* __restrict__ A,
                 const float* __restrict__ Bw,
                 const float* __restrict__ scale,
                 float* __restrict__ y)
{
    // union: max(x/y staging 64*130=8320, sP 16*8*64*2=16384) = 64 KB
    __shared__ float sU[16384];

    const int tid = threadIdx.x;
    const int bb  = tid & 63;                                  // chain in block
    const int s   = __builtin_amdgcn_readfirstlane(tid >> 6);  // segment 0..15

    // ---- stage x (fully coalesced float4) --------------------------------
    {
        const float4* xg = (const float4*)x + (size_t)blockIdx.x * 2048;
        #pragma unroll
        for (int it = 0; it < 2; ++it) {
            const int g = it * 1024 + tid;
            const float4 v = xg[g];
            const int c = g >> 5, f = (g & 31) * 4;
            *(float2*)&sU[c * 130 + f]     = make_float2(v.x, v.y);
            *(float2*)&sU[c * 130 + f + 2] = make_float2(v.z, v.w);
        }
    }
    __syncthreads();

    // ---- my 4 sites, normalized -----------------------------------------
    const int n0 = s * 4;
    float xa[4], xc[4];
    #pragma unroll
    for (int k = 0; k < 4; ++k) {
        const float2 v = *(const float2*)&sU[bb * 130 + n0 * 2 + 2 * k];
        const float inr = RSQ(v.x * v.x + v.y * v.y);
        xa[k] = v.x * inr; xc[k] = v.y * inr;
    }
    __syncthreads();   // x consumed -> sU becomes sP

    const float sc = scale[0];

    #pragma unroll 1
    for (int rep = 0; rep < REP; ++rep) {
        // opaque zero: defeats LICM/CSE across reps; value-preserving.
        float z;
        asm volatile("v_mov_b32 %0, 0" : "=v"(z));
        float xaR[4], xcR[4];
        #pragma unroll
        for (int k = 0; k < 4; ++k) { xaR[k] = xa[k] + z; xcR[k] = xc[k] + z; }

        // ---- phase 1: P = M0*M1*M2*M3 (normalized) -> sP -----------------
        {
            float P[16];
            {
                const float* Ak = A + (size_t)n0 * 32;
                BUILD_M(P, Ak, xaR[0], xcR[0]);
            }
            #pragma unroll
            for (int k = 1; k < 4; ++k) {
                float Mk[16];
                const float* Ak = A + (size_t)(n0 + k) * 32;
                BUILD_M(Mk, Ak, xaR[k], xcR[k]);
                float Pn[16];
                #pragma unroll
                for (int i = 0; i < 4; ++i) {
                    #pragma unroll
                    for (int j = 0; j < 4; ++j) {
                        float acc = P[i*4] * Mk[j];
                        acc = fmaf(P[i*4+1], Mk[4+j],  acc);
                        acc = fmaf(P[i*4+2], Mk[8+j],  acc);
                        acc = fmaf(P[i*4+3], Mk[12+j], acc);
                        Pn[i*4+j] = acc;
                    }
                }
                #pragma unroll
                for (int e = 0; e < 16; ++e) P[e] = Pn[e];
            }
            float ss = 0.f;
            #pragma unroll
            for (int e = 0; e < 16; ++e) ss = fmaf(P[e], P[e], ss);
            const float rn = RSQ(ss);
            #pragma unroll
            for (int ep = 0; ep < 8; ++ep)
                *(float2*)&sU[s * 1024 + ep * 128 + bb * 2] =
                    make_float2(P[2*ep] * rn, P[2*ep+1] * rn);
        }
        __syncthreads();

        // ---- phase 2: prefix / suffix vector scans -----------------------
        float v0 = 1.f, v1 = 0.f, v2 = 0.f, v3 = 0.f;
        #pragma unroll 1
        for (int t = 0; t < s; ++t) {
            const float* pp = &sU[t * 1024 + bb * 2];
            float p[16];
            #pragma unroll
            for (int ep = 0; ep < 8; ++ep) {
                const float2 q = *(const float2*)&pp[ep * 128];
                p[2*ep] = q.x; p[2*ep+1] = q.y;
            }
            const float w0 = v0*p[0] + v1*p[4] + v2*p[8]  + v3*p[12];
            const float w1 = v0*p[1] + v1*p[5] + v2*p[9]  + v3*p[13];
            const float w2 = v0*p[2] + v1*p[6] + v2*p[10] + v3*p[14];
            const float w3 = v0*p[3] + v1*p[7] + v2*p[11] + v3*p[15];
            const float rn = RSQ(w0*w0 + w1*w1 + w2*w2 + w3*w3);
            v0 = w0*rn; v1 = w1*rn; v2 = w2*rn; v3 = w3*rn;
        }
        float u0 = 1.f, u1 = 0.f, u2 = 0.f, u3 = 0.f;
        #pragma unroll 1
        for (int t = 15; t > s; --t) {
            const float* pp = &sU[t * 1024 + bb * 2];
            float p[16];
            #pragma unroll
            for (int ep = 0; ep < 8; ++ep) {
                const float2 q = *(const float2*)&pp[ep * 128];
                p[2*ep] = q.x; p[2*ep+1] = q.y;
            }
            const float w0 = p[0]*u0  + p[1]*u1  + p[2]*u2  + p[3]*u3;
            const float w1 = p[4]*u0  + p[5]*u1  + p[6]*u2  + p[7]*u3;
            const float w2 = p[8]*u0  + p[9]*u1  + p[10]*u2 + p[11]*u3;
            const float w3 = p[12]*u0 + p[13]*u1 + p[14]*u2 + p[15]*u3;
            const float rn = RSQ(w0*w0 + w1*w1 + w2*w2 + w3*w3);
            u0 = w0*rn; u1 = w1*rn; u2 = w2*rn; u3 = w3*rn;
        }

        // ---- phase 3a: forward walk (M recomputed) -----------------------
        float vlA[4], vlB[4], vlC[4], vlD[4];
        {
            float a0 = v0, a1 = v1, a2 = v2, a3 = v3;
            #pragma unroll
            for (int k = 0; k < 4; ++k) {
                vlA[k] = a0; vlB[k] = a1; vlC[k] = a2; vlD[k] = a3;
                if (k == 3) break;
                float Mk[16];
                const float* Ak = A + (size_t)(n0 + k) * 32;
                BUILD_M(Mk, Ak, xaR[k], xcR[k]);
                const float t0 = a0*Mk[0] + a1*Mk[4] + a2*Mk[8]  + a3*Mk[12];
                const float t1 = a0*Mk[1] + a1*Mk[5] + a2*Mk[9]  + a3*Mk[13];
                const float t2 = a0*Mk[2] + a1*Mk[6] + a2*Mk[10] + a3*Mk[14];
                const float t3 = a0*Mk[3] + a1*Mk[7] + a2*Mk[11] + a3*Mk[15];
                a0 = t0; a1 = t1; a2 = t2; a3 = t3;
            }
        }
        __syncthreads();   // scans done reading sP -> sU becomes y staging

        // ---- phase 3b: backward walk + fused epilogue --------------------
        #pragma unroll
        for (int kk = 3; kk >= 0; --kk) {
            const int n = n0 + kk;

            const float arn = RSQ(u0*u0 + u1*u1 + u2*u2 + u3*u3);
            float aa0 = u0*arn, aa1 = u1*arn, aa2 = u2*arn, aa3 = u3*arn;
            if (n == 63) { aa0 = 1.f; aa1 = aa2 = aa3 = 0.f; }

            const float wn = RSQ(vlA[kk]*vlA[kk] + vlB[kk]*vlB[kk] +
                                 vlC[kk]*vlC[kk] + vlD[kk]*vlD[kk]);
            float vv0 = vlA[kk]*wn, vv1 = vlB[kk]*wn, vv2 = vlC[kk]*wn, vv3 = vlD[kk]*wn;
            if (n == 0) { vv0 = 1.f; vv1 = vv2 = vv3 = 0.f; }

            const float vv[4] = {vv0, vv1, vv2, vv3};
            const float aa[4] = {aa0, aa1, aa2, aa3};
            const float* Bn = Bw + (size_t)n * 64;      // wave-uniform
            float H00 = 0.f, H01 = 0.f, H10 = 0.f, H11 = 0.f;
            #pragma unroll
            for (int i = 0; i < 4; ++i) {
                #pragma unroll
                for (int l = 0; l < 4; ++l) {
                    const float c = vv[i] * aa[l];
                    const int   q = (i * 4 + l) * 4;
                    H00 = fmaf(c, Bn[q + 0], H00);
                    H01 = fmaf(c, Bn[q + 1], H01);
                    H10 = fmaf(c, Bn[q + 2], H10);
                    H11 = fmaf(c, Bn[q + 3], H11);
                }
            }
            const float rh = sc * RSQ(H00*H00 + H01*H01 + H10*H10 + H11*H11);
            H00 *= rh; H01 *= rh; H10 *= rh; H11 *= rh;
            if (__builtin_isnan(H00)) H00 = 0.f;
            if (__builtin_isnan(H01)) H01 = 0.f;
            if (__builtin_isnan(H10)) H10 = 0.f;
            if (__builtin_isnan(H11)) H11 = 0.f;
            H00 = fmaxf(H00, 0.f); H01 = fmaxf(H01, 0.f);
            H10 = fmaxf(H10, 0.f); H11 = fmaxf(H11, 0.f);

            float2 yo;
            yo.x = fmaf(H01, xcR[kk], H00 * xaR[kk]);
            yo.y = fmaf(H11, xcR[kk], H10 * xaR[kk]);
            *(float2*)&sU[bb * 130 + 2 * n] = yo;

            if (kk > 0) {   // u <- M[kk].u  (raw suffix for site n-1)
                float Mk[16];
                const float* Ak = A + (size_t)(n0 + kk) * 32;
                BUILD_M(Mk, Ak, xaR[kk], xcR[kk]);
                const float t0 = Mk[0]*u0  + Mk[1]*u1  + Mk[2]*u2  + Mk[3]*u3;
                const float t1 = Mk[4]*u0  + Mk[5]*u1  + Mk[6]*u2  + Mk[7]*u3;
                const float t2 = Mk[8]*u0  + Mk[9]*u1  + Mk[10]*u2 + Mk[11]*u3;
                const float t3 = Mk[12]*u0 + Mk[13]*u1 + Mk[14]*u2 + Mk[15]*u3;
                u0 = t0; u1 = t1; u2 = t2; u3 = t3;
            }
        }
        __syncthreads();   // end-of-rep: y staging done before next sP write
    }

    // ---- y out: fully coalesced float4 stores ----------------------------
    {
        float4* yg = (float4*)y + (size_t)blockIdx.x * 2048;
        #pragma unroll
        for (int it = 0; it < 2; ++it) {
            const int g = it * 1024 + tid;
            const int c = g >> 5, f = (g & 31) * 4;
            const float2 a = *(const float2*)&sU[c * 130 + f];
            const float2 b = *(const float2*)&sU[c * 130 + f + 2];
            yg[g] = make_float4(a.x, a.y, b.x, b.y);
        }
    }
}

extern "C" void kernel_launch(void* const* d_in, const int* in_sizes, int n_in,
                              void* d_out, int out_size, void* d_ws, size_t ws_size,
                              hipStream_t stream) {
    const float* x     = (const float*)d_in[0];
    const float* A     = (const float*)d_in[1];
    const float* B     = (const float*)d_in[2];
    const float* scale = (const float*)d_in[3];
    float* yp = (float*)d_out;
    const int batch  = in_sizes[0] / 128;    // 16384
    const int blocks = batch / 64;           // 256 blocks x 1024 threads
    tdvp_kernel<<<blocks, 1024, 0, stream>>>(x, A, B, scale, yp);
}

// Round 5
// 75.750 us; speedup vs baseline: 1.6585x; 1.6585x over previous
//
#include <hip/hip_runtime.h>
#include <math.h>

// TDVP_V2: BATCH=16384 chains, N=64 sites, D=4, DIN=DOUT=2.
// v20 RESUBMIT (previous round: infra "container failed twice", no data —
// kernel cannot hang: all loop bounds compile-time/wave-uniform, barriers
// block-uniform, accesses in-bounds; resubmitting unchanged).
// CALIBRATION (v19, REP=5): tdvp_kernel dispatch = 76.5 us, VALUBusy 64%,
// VGPR=40, bank-conflicts ~0. Linear fit vs v18: harness floor = 49.1 us
// (42 us poison-fill + ~7 us small nodes), marginal rep = 12.0 us,
// single-pass kernel = 28.6 us (49.1 + 28.6 = 77.7 = v18 JSON, exact).
// Per-rep pipes: VALU issue ~5.1 us, LDS pipe ~5.3 us, rest = serial stalls
// (scan iter chain ds_read->matvec->rsq->next; M rebuilt 6x with s_load waits).
// v20 changes (REP=1):
//  1. M[4][16] register cache (VGPR 40 -> ~110, cap 128, occupancy kept):
//     kills 6 BUILD_M + A-load waits in serial walks.
//  2. Scans norm-free: only direction of v/u matters (vv/aa re-normalized in
//     epilogue; P is Frobenius-1 so <=15-term products stay in fp32 range,
//     same as reference's un-normalized binary levels). Removes 15 serial
//     rsq from the critical chain.
//  3. Prefix+suffix scans interleaved (2 independent chains, wave-uniform
//     guards) + sP stored as row-quads so each step = 4x ds_read_b128
//     (contiguous 1KB/wave, conflict-free).
// Predicted: kernel 28.6 -> ~23-25 us => JSON ~72-74. absmax ~0.004.

#define RSQ(x) __builtin_amdgcn_rsqf((x) + 1e-30f)

__global__ __launch_bounds__(1024, 4)
void tdvp_kernel(const float* __restrict__ x,
                 const float* __restrict__ A,
                 const float* __restrict__ Bw,
                 const float* __restrict__ scale,
                 float* __restrict__ y)
{
    // union: x/y staging [64 chains][130] (33KB)  /  sP [16 t][4 q][64 bb][4] (64KB)
    __shared__ float sU[16384];

    const int tid = threadIdx.x;
    const int bb  = tid & 63;                                  // chain in block
    const int s   = __builtin_amdgcn_readfirstlane(tid >> 6);  // segment 0..15

    // ---- stage x (fully coalesced float4) --------------------------------
    {
        const float4* xg = (const float4*)x + (size_t)blockIdx.x * 2048;
        #pragma unroll
        for (int it = 0; it < 2; ++it) {
            const int g = it * 1024 + tid;
            const float4 v = xg[g];
            const int c = g >> 5, f = (g & 31) * 4;
            *(float2*)&sU[c * 130 + f]     = make_float2(v.x, v.y);
            *(float2*)&sU[c * 130 + f + 2] = make_float2(v.z, v.w);
        }
    }
    __syncthreads();

    // ---- my 4 sites, normalized -----------------------------------------
    const int n0 = s * 4;
    float xa[4], xc[4];
    #pragma unroll
    for (int k = 0; k < 4; ++k) {
        const float2 v = *(const float2*)&sU[bb * 130 + n0 * 2 + 2 * k];
        const float inr = RSQ(v.x * v.x + v.y * v.y);
        xa[k] = v.x * inr; xc[k] = v.y * inr;
    }
    __syncthreads();   // x consumed -> sU becomes sP

    // ---- M cache: built once, used by phase 1 + both walks ---------------
    float M[4][16];
    #pragma unroll
    for (int k = 0; k < 4; ++k) {
        const float* Ak = A + (size_t)(n0 + k) * 32;   // wave-uniform -> s_load
        #pragma unroll
        for (int e = 0; e < 16; ++e)
            M[k][e] = fmaf(xc[k], Ak[2*e+1], xa[k] * Ak[2*e]);
    }

    // ---- phase 1: P = M0*M1*M2*M3, Frobenius-normalized -> sP ------------
    {
        float P[16];
        #pragma unroll
        for (int e = 0; e < 16; ++e) P[e] = M[0][e];
        #pragma unroll
        for (int k = 1; k < 4; ++k) {
            float Pn[16];
            #pragma unroll
            for (int i = 0; i < 4; ++i) {
                #pragma unroll
                for (int j = 0; j < 4; ++j) {
                    float acc = P[i*4] * M[k][j];
                    acc = fmaf(P[i*4+1], M[k][4+j],  acc);
                    acc = fmaf(P[i*4+2], M[k][8+j],  acc);
                    acc = fmaf(P[i*4+3], M[k][12+j], acc);
                    Pn[i*4+j] = acc;
                }
            }
            #pragma unroll
            for (int e = 0; e < 16; ++e) P[e] = Pn[e];
        }
        float ss = 0.f;
        #pragma unroll
        for (int e = 0; e < 16; ++e) ss = fmaf(P[e], P[e], ss);
        const float rn = RSQ(ss);
        // row-quad layout: row q of P at sU[s*1024 + q*256 + bb*4]
        #pragma unroll
        for (int q = 0; q < 4; ++q)
            *(float4*)&sU[s * 1024 + q * 256 + bb * 4] =
                make_float4(P[4*q]*rn, P[4*q+1]*rn, P[4*q+2]*rn, P[4*q+3]*rn);
    }
    __syncthreads();

    // ---- phase 2: interleaved prefix/suffix scans, norm-free -------------
    float v0 = 1.f, v1 = 0.f, v2 = 0.f, v3 = 0.f;   // prefix: v <- v * P_t
    float u0 = 1.f, u1 = 0.f, u2 = 0.f, u3 = 0.f;   // suffix: u <- P_t * u
    const int nsuf = 15 - s;
    #pragma unroll 1
    for (int i = 0; i < 15; ++i) {
        if (i < s) {               // wave-uniform
            const float4* pp = (const float4*)&sU[i * 1024 + bb * 4];
            const float4 r0 = pp[0], r1 = pp[64], r2 = pp[128], r3 = pp[192];
            const float w0 = v0*r0.x + v1*r1.x + v2*r2.x + v3*r3.x;
            const float w1 = v0*r0.y + v1*r1.y + v2*r2.y + v3*r3.y;
            const float w2 = v0*r0.z + v1*r1.z + v2*r2.z + v3*r3.z;
            const float w3 = v0*r0.w + v1*r1.w + v2*r2.w + v3*r3.w;
            v0 = w0; v1 = w1; v2 = w2; v3 = w3;
        }
        if (i < nsuf) {            // wave-uniform, t = 15 - i
            const float4* pp = (const float4*)&sU[(15 - i) * 1024 + bb * 4];
            const float4 r0 = pp[0], r1 = pp[64], r2 = pp[128], r3 = pp[192];
            const float w0 = r0.x*u0 + r0.y*u1 + r0.z*u2 + r0.w*u3;
            const float w1 = r1.x*u0 + r1.y*u1 + r1.z*u2 + r1.w*u3;
            const float w2 = r2.x*u0 + r2.y*u1 + r2.z*u2 + r2.w*u3;
            const float w3 = r3.x*u0 + r3.y*u1 + r3.z*u2 + r3.w*u3;
            u0 = w0; u1 = w1; u2 = w2; u3 = w3;
        }
    }

    // ---- phase 3a: forward walk, vl per site (cached M, raw) -------------
    float vlA[4], vlB[4], vlC[4], vlD[4];
    {
        float a0 = v0, a1 = v1, a2 = v2, a3 = v3;
        #pragma unroll
        for (int k = 0; k < 4; ++k) {
            vlA[k] = a0; vlB[k] = a1; vlC[k] = a2; vlD[k] = a3;
            if (k == 3) break;
            const float t0 = a0*M[k][0] + a1*M[k][4] + a2*M[k][8]  + a3*M[k][12];
            const float t1 = a0*M[k][1] + a1*M[k][5] + a2*M[k][9]  + a3*M[k][13];
            const float t2 = a0*M[k][2] + a1*M[k][6] + a2*M[k][10] + a3*M[k][14];
            const float t3 = a0*M[k][3] + a1*M[k][7] + a2*M[k][11] + a3*M[k][15];
            a0 = t0; a1 = t1; a2 = t2; a3 = t3;
        }
    }
    __syncthreads();   // scans done reading sP -> sU becomes y staging

    // ---- phase 3b: backward walk + fused epilogue (cached M) -------------
    const float sc = scale[0];
    #pragma unroll
    for (int kk = 3; kk >= 0; --kk) {
        const int n = n0 + kk;

        const float arn = RSQ(u0*u0 + u1*u1 + u2*u2 + u3*u3);
        float aa0 = u0*arn, aa1 = u1*arn, aa2 = u2*arn, aa3 = u3*arn;
        if (n == 63) { aa0 = 1.f; aa1 = aa2 = aa3 = 0.f; }

        const float wn = RSQ(vlA[kk]*vlA[kk] + vlB[kk]*vlB[kk] +
                             vlC[kk]*vlC[kk] + vlD[kk]*vlD[kk]);
        float vv0 = vlA[kk]*wn, vv1 = vlB[kk]*wn, vv2 = vlC[kk]*wn, vv3 = vlD[kk]*wn;
        if (n == 0) { vv0 = 1.f; vv1 = vv2 = vv3 = 0.f; }

        const float vv[4] = {vv0, vv1, vv2, vv3};
        const float aa[4] = {aa0, aa1, aa2, aa3};
        const float* Bn = Bw + (size_t)n * 64;      // wave-uniform -> s_load
        float H00 = 0.f, H01 = 0.f, H10 = 0.f, H11 = 0.f;
        #pragma unroll
        for (int i = 0; i < 4; ++i) {
            #pragma unroll
            for (int l = 0; l < 4; ++l) {
                const float c = vv[i] * aa[l];
                const int   q = (i * 4 + l) * 4;
                H00 = fmaf(c, Bn[q + 0], H00);
                H01 = fmaf(c, Bn[q + 1], H01);
                H10 = fmaf(c, Bn[q + 2], H10);
                H11 = fmaf(c, Bn[q + 3], H11);
            }
        }
        const float rh = sc * RSQ(H00*H00 + H01*H01 + H10*H10 + H11*H11);
        H00 *= rh; H01 *= rh; H10 *= rh; H11 *= rh;
        if (__builtin_isnan(H00)) H00 = 0.f;
        if (__builtin_isnan(H01)) H01 = 0.f;
        if (__builtin_isnan(H10)) H10 = 0.f;
        if (__builtin_isnan(H11)) H11 = 0.f;
        H00 = fmaxf(H00, 0.f); H01 = fmaxf(H01, 0.f);
        H10 = fmaxf(H10, 0.f); H11 = fmaxf(H11, 0.f);

        float2 yo;
        yo.x = fmaf(H01, xc[kk], H00 * xa[kk]);
        yo.y = fmaf(H11, xc[kk], H10 * xa[kk]);
        *(float2*)&sU[bb * 130 + 2 * n] = yo;

        if (kk > 0) {   // u <- M[kk].u  (raw suffix for site n-1)
            const float t0 = M[kk][0]*u0  + M[kk][1]*u1  + M[kk][2]*u2  + M[kk][3]*u3;
            const float t1 = M[kk][4]*u0  + M[kk][5]*u1  + M[kk][6]*u2  + M[kk][7]*u3;
            const float t2 = M[kk][8]*u0  + M[kk][9]*u1  + M[kk][10]*u2 + M[kk][11]*u3;
            const float t3 = M[kk][12]*u0 + M[kk][13]*u1 + M[kk][14]*u2 + M[kk][15]*u3;
            u0 = t0; u1 = t1; u2 = t2; u3 = t3;
        }
    }
    __syncthreads();

    // ---- y out: fully coalesced float4 stores ----------------------------
    {
        float4* yg = (float4*)y + (size_t)blockIdx.x * 2048;
        #pragma unroll
        for (int it = 0; it < 2; ++it) {
            const int g = it * 1024 + tid;
            const int c = g >> 5, f = (g & 31) * 4;
            const float2 a = *(const float2*)&sU[c * 130 + f];
            const float2 b = *(const float2*)&sU[c * 130 + f + 2];
            yg[g] = make_float4(a.x, a.y, b.x, b.y);
        }
    }
}

extern "C" void kernel_launch(void* const* d_in, const int* in_sizes, int n_in,
                              void* d_out, int out_size, void* d_ws, size_t ws_size,
                              hipStream_t stream) {
    const float* x     = (const float*)d_in[0];
    const float* A     = (const float*)d_in[1];
    const float* B     = (const float*)d_in[2];
    const float* scale = (const float*)d_in[3];
    float* yp = (float*)d_out;
    const int batch  = in_sizes[0] / 128;    // 16384
    const int blocks = batch / 64;           // 256 blocks x 1024 threads
    tdvp_kernel<<<blocks, 1024, 0, stream>>>(x, A, B, scale, yp);
}